// Round 9
// baseline (219.852 us; speedup 1.0000x reference)
//
#include <hip/hip_runtime.h>

// MemoryEfficientAttention: x->(Q,K,V) proj (bf16 MFMA, scale*log2e folded into Q),
// chunked-mask flash attention (double-swapped MFMA, exp2-domain lane-local softmax,
// QBLK=128: 2 q-sets/wave amortize per-tile overhead; R5-proven dbuf+barrier),
// O-proj (split-A bf16x2 MFMA, 128x64 tile). fp32 in/out.
// Mask: past blocks masked, diagonal block causal, future blocks visible.

typedef __attribute__((ext_vector_type(8))) short bf16x8;
typedef __attribute__((ext_vector_type(4))) float f32x4;
typedef __attribute__((ext_vector_type(4))) float float4v;
typedef __attribute__((ext_vector_type(4))) unsigned short u16x4;

__device__ __forceinline__ unsigned short f2bf(float x){
  union { float f; unsigned int u; } c; c.f = x;
  unsigned int r = c.u + 0x7FFFu + ((c.u >> 16) & 1u);
  return (unsigned short)(r >> 16);
}
__device__ __forceinline__ float bf2f(unsigned short h){
  union { unsigned int u; float f; } c; c.u = ((unsigned int)h) << 16;
  return c.f;
}
__device__ __forceinline__ f32x4 zero4(){ f32x4 v; v[0]=0.f; v[1]=0.f; v[2]=0.f; v[3]=0.f; return v; }
__device__ __forceinline__ unsigned int cvtpk(float a, float b){
  unsigned int r;
  asm("v_cvt_pk_bf16_f32 %0, %1, %2" : "=v"(r) : "v"(a), "v"(b));
  return r;
}
__device__ __forceinline__ float exp2x(float x){   // raw v_exp_f32 = 2^x
  float r;
  asm("v_exp_f32 %0, %1" : "=v"(r) : "v"(x));
  return r;
}

// async global->LDS, 16B per lane; LDS dest wave-uniform, global src per-lane
#define GLDS16(g, l) __builtin_amdgcn_global_load_lds( \
  (const __attribute__((address_space(1))) void*)(g), \
  (__attribute__((address_space(3))) void*)(l), 16, 0, 0)

// ---------------- prep: cast x and all weights to bf16, gather biases ----------------
__global__ __launch_bounds__(256) void k_prep(
    const float* __restrict__ x,
    const float* __restrict__ Wq, const float* __restrict__ Wk,
    const float* __restrict__ Wv, const float* __restrict__ Wo,
    const float* __restrict__ bq, const float* __restrict__ bk, const float* __restrict__ bv,
    unsigned short* __restrict__ xh, unsigned short* __restrict__ wh,
    float* __restrict__ bias_cat){
  const int NX = 1048576;                     // x float4 count (4096*1024/4)
  const int NTOT = 2097152;                   // + 4 weight matrices
  int i = blockIdx.x * 256 + threadIdx.x;
  if (i < 3072){
    const float* bs[3] = {bq, bk, bv};
    bias_cat[i] = bs[i >> 10][i & 1023];
  }
  int stride = gridDim.x * 256;
  for (; i < NTOT; i += stride){
    float4v v;
    u16x4 h;
    if (i < NX){
      v = ((const float4v*)x)[i];
      #pragma unroll
      for (int j = 0; j < 4; ++j) h[j] = f2bf(v[j]);
      ((u16x4*)xh)[i] = h;
    } else {
      int jj = i - NX;
      const float* srcs[4] = {Wq, Wk, Wv, Wo};
      v = ((const float4v*)srcs[jj >> 18])[jj & 0x3FFFF];
      #pragma unroll
      for (int j = 0; j < 4; ++j) h[j] = f2bf(v[j]);
      ((u16x4*)wh)[jj] = h;
    }
  }
}

// ---------------- GEMM: out = A @ W^T + bias ----------------
// MODE 0: N=3072 fused QKV -> scatter Q[b,h,t,d]*scale*log2e, K[b,h,t,d], Vt[b,h,d,t]
// MODE 1: N=1024 -> fp32 out + bias
template<int BM, int BN, int MODE, int SPLITA>
__global__ __launch_bounds__(256) void k_gemm(
    const unsigned short* __restrict__ Ah, const unsigned short* __restrict__ Al,
    const unsigned short* __restrict__ Bh,
    const float* __restrict__ bias, const float* __restrict__ scale_p,
    unsigned short* __restrict__ oq, unsigned short* __restrict__ okk,
    unsigned short* __restrict__ ov, float* __restrict__ fo)
{
  constexpr int MF = (BN == 128) ? (BM/32) : (BM/64);
  constexpr int NF = 4;
  constexpr int AISS = BM/64;
  constexpr int BISS = BN/64;
  constexpr int NA = SPLITA ? 2 : 1;
  __shared__ unsigned short As[NA][BM*32];
  __shared__ unsigned short Bs[BN*32];

  const int tid  = threadIdx.x;
  const int wid  = tid >> 6;
  const int lane = tid & 63;
  const int l15  = lane & 15;
  const int kg   = lane >> 4;
  const int m0 = blockIdx.y * BM;
  const int n0 = blockIdx.x * BN;
  const int wrb = (BN == 128) ? (wid >> 1) * (BM/2) : wid * (BM/4);
  const int wcb = (BN == 128) ? (wid & 1) * 64 : 0;
  const float qs = (MODE == 0) ? scale_p[0] * 1.4426950408889634f : 0.f;  // fold log2e

  f32x4 acc[MF][NF];
  #pragma unroll
  for (int a = 0; a < MF; ++a)
    #pragma unroll
    for (int b = 0; b < NF; ++b) acc[a][b] = zero4();

  for (int k0 = 0; k0 < 1024; k0 += 32){
    #pragma unroll
    for (int p = 0; p < NA; ++p){
      const unsigned short* Asrc = p ? Al : Ah;
      #pragma unroll
      for (int iss = 0; iss < AISS; ++iss){
        int L = iss*2048 + tid*8;
        int row = L >> 5;
        int ck = ((L >> 3) & 3) ^ ((row >> 1) & 3);
        GLDS16(Asrc + (size_t)(m0 + row)*1024 + k0 + ck*8,
               (char*)(&As[p][0]) + iss*4096 + wid*1024);
      }
    }
    #pragma unroll
    for (int iss = 0; iss < BISS; ++iss){
      int L = iss*2048 + tid*8;
      int row = L >> 5;
      int ck = ((L >> 3) & 3) ^ ((row >> 1) & 3);
      GLDS16(Bh + (size_t)(n0 + row)*1024 + k0 + ck*8,
             (char*)(&Bs[0]) + iss*4096 + wid*1024);
    }
    __syncthreads();

    bf16x8 af[MF][NA];
    #pragma unroll
    for (int mf = 0; mf < MF; ++mf){
      int r = wrb + mf*16 + l15;
      int ckpos = kg ^ ((r >> 1) & 3);
      #pragma unroll
      for (int p = 0; p < NA; ++p)
        af[mf][p] = *(const bf16x8*)((const char*)(&As[p][0]) + r*64 + ckpos*16);
    }
    #pragma unroll
    for (int nf = 0; nf < NF; ++nf){
      int r = wcb + nf*16 + l15;
      int ckpos = kg ^ ((r >> 1) & 3);
      bf16x8 bhv = *(const bf16x8*)((const char*)(&Bs[0]) + r*64 + ckpos*16);
      #pragma unroll
      for (int mf = 0; mf < MF; ++mf){
        acc[mf][nf] = __builtin_amdgcn_mfma_f32_16x16x32_bf16(af[mf][0], bhv, acc[mf][nf], 0,0,0);
        if (SPLITA)
          acc[mf][nf] = __builtin_amdgcn_mfma_f32_16x16x32_bf16(af[mf][1], bhv, acc[mf][nf], 0,0,0);
      }
    }
    __syncthreads();
  }

  #pragma unroll
  for (int mf = 0; mf < MF; ++mf){
    #pragma unroll
    for (int nf = 0; nf < NF; ++nf){
      int colg = n0 + wcb + nf*16 + l15;
      float bb = bias[colg];
      #pragma unroll
      for (int j = 0; j < 4; ++j){
        int r = m0 + wrb + mf*16 + kg*4 + j;
        float val = acc[mf][nf][j] + bb;
        if (MODE == 1){
          fo[(size_t)r*1024 + colg] = val;
        } else {
          int bi = r >> 11, tt = r & 2047;
          int mat = colg >> 10, jj = colg & 1023;
          int h = jj >> 6, d = jj & 63;
          size_t bh_ = (size_t)(bi*16 + h);
          if (mat == 0)      oq [(bh_*2048 + tt)*64 + d] = f2bf(val * qs);
          else if (mat == 1) okk[(bh_*2048 + tt)*64 + d] = f2bf(val);
          else               ov [(bh_*64 + d)*2048 + tt] = f2bf(val);  // V^T
        }
      }
    }
  }
}

// softmax step for one q-set: pmax, defer-rescale, exp2, pack, P-write (wave-private)
#define SOFTMAX_STEP(ST_, m_, l_, O_, pw_) do { \
  float _x0 = fmaxf(fmaxf(ST_[0][0],ST_[0][1]), fmaxf(ST_[0][2],ST_[0][3])); \
  float _x1 = fmaxf(fmaxf(ST_[1][0],ST_[1][1]), fmaxf(ST_[1][2],ST_[1][3])); \
  float _x2 = fmaxf(fmaxf(ST_[2][0],ST_[2][1]), fmaxf(ST_[2][2],ST_[2][3])); \
  float _x3 = fmaxf(fmaxf(ST_[3][0],ST_[3][1]), fmaxf(ST_[3][2],ST_[3][3])); \
  float _pm = fmaxf(fmaxf(_x0,_x1), fmaxf(_x2,_x3)); \
  _pm = fmaxf(_pm, __shfl_xor(_pm, 16, 64)); \
  _pm = fmaxf(_pm, __shfl_xor(_pm, 32, 64)); \
  if (!__all(_pm <= m_ + 8.0f)){ \
    float _mn = fmaxf(m_, _pm); \
    float _fj = exp2x(m_ - _mn); \
    m_ = _mn; l_ *= _fj; \
    _Pragma("unroll") \
    for (int _d = 0; _d < 4; ++_d) \
      _Pragma("unroll") \
      for (int _j = 0; _j < 4; ++_j) O_[_d][_j] *= _fj; \
  } \
  unsigned int _pk[4][2]; \
  float _rt = 0.f; \
  _Pragma("unroll") \
  for (int _n = 0; _n < 4; ++_n){ \
    float _p0 = exp2x(ST_[_n][0] - m_), _p1 = exp2x(ST_[_n][1] - m_); \
    float _p2 = exp2x(ST_[_n][2] - m_), _p3 = exp2x(ST_[_n][3] - m_); \
    _rt += (_p0 + _p1) + (_p2 + _p3); \
    _pk[_n][0] = cvtpk(_p0, _p1); \
    _pk[_n][1] = cvtpk(_p2, _p3); \
  } \
  _rt += __shfl_xor(_rt, 16, 64); \
  _rt += __shfl_xor(_rt, 32, 64); \
  l_ += _rt; \
  _Pragma("unroll") \
  for (int _n = 0; _n < 4; ++_n) \
    *(uint2*)(pw_ + (pws ^ (_n*32))) = make_uint2(_pk[_n][0], _pk[_n][1]); \
} while(0)

// QK for one q-set from Ks[buf]
#define QK_STEP(ST_, qlo_, qhi_) do { \
  _Pragma("unroll") \
  for (int _n = 0; _n < 4; ++_n) ST_[_n] = zero4(); \
  __builtin_amdgcn_s_setprio(1); \
  _Pragma("unroll") \
  for (int _n = 0; _n < 4; ++_n){ \
    bf16x8 _ak = *(const bf16x8*)(ksb + _n*2048 + c0); \
    ST_[_n] = __builtin_amdgcn_mfma_f32_16x16x32_bf16(_ak, qlo_, ST_[_n], 0,0,0); \
  } \
  _Pragma("unroll") \
  for (int _n = 0; _n < 4; ++_n){ \
    bf16x8 _ak = *(const bf16x8*)(ksb + _n*2048 + c1); \
    ST_[_n] = __builtin_amdgcn_mfma_f32_16x16x32_bf16(_ak, qhi_, ST_[_n], 0,0,0); \
  } \
  __builtin_amdgcn_s_setprio(0); \
} while(0)

// ---------------- flash attention, QBLK=128 (2 q-sets/wave) ----------------
// grid: 512 = p(16) x bh(32); qt = p<8 ? p : 23-p so the 2 concurrent blocks/CU
// sum to a constant 34 KV-tiles. Block owns q-chunks qc0=2qt, qc1=2qt+1.
// Set0 = chunk qc0 (waves x 16q), set1 = chunk qc1. Set1 skips kb==qc0 (past-masked).
// ST = mfma(K,Q): col=l15=q, row=kg*4+j=k.  Ot = mfma(V^T,P^T): col=l15=q, row=d.
// K/V fragments are read once per tile and reused by both q-sets.
__global__ __launch_bounds__(256) void k_attn(
    const unsigned short* __restrict__ Qg, const unsigned short* __restrict__ Kg,
    const unsigned short* __restrict__ Vtg,
    unsigned short* __restrict__ Ohi, unsigned short* __restrict__ Olo)
{
  __shared__ unsigned short Qs[8192];        // 128q x 64d (16KB) -> P tiles after reg load
  __shared__ unsigned short Ks[2][4096];     // K dbuf
  __shared__ unsigned short Vts[2][4096];    // V^T dbuf (rows=d, cols=kv)

  const int tid  = threadIdx.x;
  const int wid  = tid >> 6;
  const int lane = tid & 63;
  const int l15  = lane & 15;
  const int kg   = lane >> 4;
  const int p  = blockIdx.x >> 5;
  const int qt = (p < 8) ? p : 23 - p;       // concurrent-pair load balance
  const int bh = blockIdx.x & 31;
  const size_t base = (size_t)bh * (2048*64);
  const int qc0 = 2*qt, qc1 = 2*qt + 1;

  // staging: per-lane swizzled global source, linear LDS dest
  const int r0 = tid >> 3;                   // staging row (each call site: 32 rows)
  const int ck = ((tid & 7) ^ (r0 & 7)) * 8;
  const unsigned short* qp = Qg  + base + (size_t)(qc0*64 + r0)*64 + ck;
  const unsigned short* kp = Kg  + base + (size_t)(qc0*64 + r0)*64 + ck;
  const unsigned short* vp = Vtg + base + (size_t)r0*2048 + qc0*64 + ck;
  GLDS16(qp,         (char*)Qs + wid*1024);
  GLDS16(qp + 2048,  (char*)Qs + wid*1024 + 4096);
  GLDS16(qp + 4096,  (char*)Qs + wid*1024 + 8192);
  GLDS16(qp + 6144,  (char*)Qs + wid*1024 + 12288);
  GLDS16(kp,         (char*)Ks  + wid*1024);
  GLDS16(kp + 2048,  (char*)Ks  + wid*1024 + 4096);
  GLDS16(vp,         (char*)Vts + wid*1024);
  GLDS16(vp + 65536, (char*)Vts + wid*1024 + 4096);
  kp += 4096;  vp += 64;                     // -> chunk qc0+1
  __syncthreads();

  const int c0 = (kg ^ (l15 & 7)) << 4;
  const int c1 = c0 ^ 64;
  const char* qb0 = (const char*)Qs + wid*2048 + l15*128;        // set0 slice
  const char* qb1 = qb0 + 8192;                                  // set1 slice
  char* pw0 = (char*)Qs + wid*2048 + l15*128;                    // P0 (reuses Q LDS)
  char* pw1 = pw0 + 8192;                                        // P1
  const int pws = (kg*8) ^ ((l15 & 7) << 4);
  const int qloc = wid*16 + l15;             // within-chunk q row (same both sets)

  // Q fragments to registers (then LDS slices become P buffers)
  const bf16x8 qA0 = *(const bf16x8*)(qb0 + c0);
  const bf16x8 qA1 = *(const bf16x8*)(qb0 + c1);
  const bf16x8 qB0 = *(const bf16x8*)(qb1 + c0);
  const bf16x8 qB1 = *(const bf16x8*)(qb1 + c1);

  f32x4 O0[4], O1[4];
  #pragma unroll
  for (int d = 0; d < 4; ++d){ O0[d] = zero4(); O1[d] = zero4(); }
  float m0 = -1e30f, l0 = 0.f, m1 = -1e30f, l1 = 0.f;

  for (int kb = qc0; kb < 32; ++kb){
    const int buf = (kb - qc0) & 1;
    const char* ksb = (const char*)Ks  + buf*8192 + l15*128;
    const char* vsb = (const char*)Vts + buf*8192 + l15*128;
    const bool act1 = (kb >= qc1);
    // prefetch next K/V into other buffer (drained by closing barrier)
    if (kb + 1 < 32){
      char* dK = (char*)Ks  + (buf^1)*8192 + wid*1024;
      char* dV = (char*)Vts + (buf^1)*8192 + wid*1024;
      GLDS16(kp,         dK);
      GLDS16(kp + 2048,  dK + 4096);
      GLDS16(vp,         dV);
      GLDS16(vp + 65536, dV + 4096);
      kp += 4096;  vp += 64;
    }
    // ---- set0: QK, (diag mask), softmax, P-write ----
    {
      f32x4 ST[4];
      QK_STEP(ST, qA0, qA1);
      if (kb == qc0){
        #pragma unroll
        for (int nf = 0; nf < 4; ++nf)
          #pragma unroll
          for (int j = 0; j < 4; ++j)
            if (nf*16 + kg*4 + j > qloc) ST[nf][j] = -1e30f;
      }
      SOFTMAX_STEP(ST, m0, l0, O0, pw0);
    }
    // ---- set1 (skip tile kb==qc0: fully past-masked) ----
    if (act1){
      f32x4 ST[4];
      QK_STEP(ST, qB0, qB1);
      if (kb == qc1){
        #pragma unroll
        for (int nf = 0; nf < 4; ++nf)
          #pragma unroll
          for (int j = 0; j < 4; ++j)
            if (nf*16 + kg*4 + j > qloc) ST[nf][j] = -1e30f;
      }
      SOFTMAX_STEP(ST, m1, l1, O1, pw1);
    }
    // ---- PV: V fragments read once, applied to both sets ----
    {
      bf16x8 pa00 = *(const bf16x8*)(qb0 + c0);
      bf16x8 pa01 = *(const bf16x8*)(qb0 + c1);
      if (act1){
        bf16x8 pa10 = *(const bf16x8*)(qb1 + c0);
        bf16x8 pa11 = *(const bf16x8*)(qb1 + c1);
        __builtin_amdgcn_s_setprio(1);
        #pragma unroll
        for (int df = 0; df < 4; ++df){
          bf16x8 vb = *(const bf16x8*)(vsb + df*2048 + c0);
          O0[df] = __builtin_amdgcn_mfma_f32_16x16x32_bf16(vb, pa00, O0[df], 0,0,0);
          O1[df] = __builtin_amdgcn_mfma_f32_16x16x32_bf16(vb, pa10, O1[df], 0,0,0);
        }
        #pragma unroll
        for (int df = 0; df < 4; ++df){
          bf16x8 vb = *(const bf16x8*)(vsb + df*2048 + c1);
          O0[df] = __builtin_amdgcn_mfma_f32_16x16x32_bf16(vb, pa01, O0[df], 0,0,0);
          O1[df] = __builtin_amdgcn_mfma_f32_16x16x32_bf16(vb, pa11, O1[df], 0,0,0);
        }
        __builtin_amdgcn_s_setprio(0);
      } else {
        __builtin_amdgcn_s_setprio(1);
        #pragma unroll
        for (int df = 0; df < 4; ++df){
          bf16x8 vb = *(const bf16x8*)(vsb + df*2048 + c0);
          O0[df] = __builtin_amdgcn_mfma_f32_16x16x32_bf16(vb, pa00, O0[df], 0,0,0);
        }
        #pragma unroll
        for (int df = 0; df < 4; ++df){
          bf16x8 vb = *(const bf16x8*)(vsb + df*2048 + c1);
          O0[df] = __builtin_amdgcn_mfma_f32_16x16x32_bf16(vb, pa01, O0[df], 0,0,0);
        }
        __builtin_amdgcn_s_setprio(0);
      }
    }
    __syncthreads();   // drains prefetch + all waves' reads of buf
  }

  // epilogue: O /= l (lane-local), hi/lo split, 8B vector stores; both q-sets
  const int bi = bh >> 4, h = bh & 15;
  #pragma unroll
  for (int set = 0; set < 2; ++set){
    const float rinv = 1.0f / (set ? l1 : l0);
    const f32x4* O = set ? O1 : O0;
    const size_t row = (size_t)(bi*2048 + (qc0 + set)*64 + qloc);
    #pragma unroll
    for (int df = 0; df < 4; ++df){
      int colb = h*64 + df*16 + kg*4;
      u16x4 hv, lv;
      #pragma unroll
      for (int j = 0; j < 4; ++j){
        float v = O[df][j] * rinv;
        unsigned short hvv = f2bf(v);
        hv[j] = hvv;
        lv[j] = f2bf(v - bf2f(hvv));
      }
      *(u16x4*)(Ohi + row*1024 + colb) = hv;
      *(u16x4*)(Olo + row*1024 + colb) = lv;
    }
  }
}

extern "C" void kernel_launch(void* const* d_in, const int* in_sizes, int n_in,
                              void* d_out, int out_size, void* d_ws, size_t ws_size,
                              hipStream_t stream){
  const float* x  = (const float*)d_in[0];
  const float* Wq = (const float*)d_in[1];
  const float* bq = (const float*)d_in[2];
  const float* Wk = (const float*)d_in[3];
  const float* bk = (const float*)d_in[4];
  const float* Wv = (const float*)d_in[5];
  const float* bv = (const float*)d_in[6];
  const float* Wo = (const float*)d_in[7];
  const float* bo = (const float*)d_in[8];
  const float* scale = (const float*)d_in[9];
  float* out = (float*)d_out;

  char* ws = (char*)d_ws;
  const size_t MB = 1024*1024;
  unsigned short* xh  = (unsigned short*)(ws + 0*MB);    // 8 MB
  unsigned short* wh  = (unsigned short*)(ws + 16*MB);   // 8 MB (Wq,Wk,Wv,Wo bf16)
  unsigned short* Qb  = (unsigned short*)(ws + 32*MB);
  unsigned short* Kb  = (unsigned short*)(ws + 40*MB);
  unsigned short* Vtb = (unsigned short*)(ws + 48*MB);
  unsigned short* Ohi = (unsigned short*)(ws + 56*MB);
  unsigned short* Olo = (unsigned short*)(ws + 64*MB);
  float* bias_cat     = (float*)(ws + 72*MB);

  hipLaunchKernelGGL(k_prep, dim3(2048), dim3(256), 0, stream,
                     x, Wq, Wk, Wv, Wo, bq, bk, bv, xh, wh, bias_cat);
  hipLaunchKernelGGL((k_gemm<128,128,0,0>), dim3(24,32), dim3(256), 0, stream,
                     xh, (const unsigned short*)nullptr, wh, bias_cat, scale,
                     Qb, Kb, Vtb, (float*)nullptr);
  hipLaunchKernelGGL(k_attn, dim3(512), dim3(256), 0, stream, Qb, Kb, Vtb, Ohi, Olo);
  hipLaunchKernelGGL((k_gemm<128,64,1,1>), dim3(16,32), dim3(256), 0, stream,
                     Ohi, Olo, wh + 3u*1048576u, bo, (const float*)nullptr,
                     (unsigned short*)nullptr, (unsigned short*)nullptr,
                     (unsigned short*)nullptr, out);
}